// Round 4
// baseline (852.760 us; speedup 1.0000x reference)
//
#include <hip/hip_runtime.h>
#include <hip/hip_bf16.h>
#include <math.h>

// EnhancedSparseMoE round 4 (= round 3 retry, typedef collision fixed):
// single-barrier double-buffered K-loop, fp32 weights converted in-register
// during staging (no cvt passes), gating fused with x->bf16.
// T=2048, H=2048, I=1408, E=8, top-2.
#define T_TOK 2048
#define H_DIM 2048
#define I_DIM 1408
#define E_NUM 8
#define I2    2816   // 2*I

typedef __attribute__((ext_vector_type(8))) short short8;
typedef __attribute__((ext_vector_type(4))) float floatx4;
typedef __attribute__((ext_vector_type(8))) unsigned short bhalf8;
typedef __attribute__((ext_vector_type(4))) unsigned short bhalf4;
typedef unsigned short u16;

__device__ __forceinline__ u16 f2bf(float x) {   // RNE, == __float2bfloat16
    unsigned u = __builtin_bit_cast(unsigned, x);
    return (u16)((u + 0x7FFFu + ((u >> 16) & 1u)) >> 16);
}
__device__ __forceinline__ bhalf8 pack8(float4 a, float4 b) {
    bhalf8 o;
    o[0] = f2bf(a.x); o[1] = f2bf(a.y); o[2] = f2bf(a.z); o[3] = f2bf(a.w);
    o[4] = f2bf(b.x); o[5] = f2bf(b.y); o[6] = f2bf(b.z); o[7] = f2bf(b.w);
    return o;
}
__device__ __forceinline__ floatx4 mfma16(short8 a, short8 b, floatx4 c) {
    return __builtin_amdgcn_mfma_f32_16x16x32_bf16(a, b, c, 0, 0, 0);
}
__device__ __forceinline__ void gload16(const u16* g, u16* l) {
    __builtin_amdgcn_global_load_lds(
        (const __attribute__((address_space(1))) unsigned int*)g,
        (__attribute__((address_space(3))) unsigned int*)l, 16, 0, 0);
}
// 16B-chunk swizzle: row r, logical chunk c stored at phys chunk c ^ swz(r)
__device__ __forceinline__ int swz(int r) { return (r & 3) ^ ((r >> 2) & 3); }

// ---------------- gating (fp32 exact) + x -> bf16 ----------------
__global__ void moe_gating(const float* __restrict__ x, const float* __restrict__ gw,
                           float* __restrict__ wts, int* __restrict__ counts,
                           int* __restrict__ entries, u16* __restrict__ xb) {
    const int lane = threadIdx.x & 63;
    const int wv   = threadIdx.x >> 6;
    const int t    = blockIdx.x * 4 + wv;
    float acc[E_NUM];
#pragma unroll
    for (int e = 0; e < E_NUM; ++e) acc[e] = 0.f;
    const float4* xr = (const float4*)(x + (size_t)t * H_DIM);
#pragma unroll
    for (int j = 0; j < 8; ++j) {
        float4 xv = xr[lane + 64 * j];
        bhalf4 xo;
        xo[0] = f2bf(xv.x); xo[1] = f2bf(xv.y); xo[2] = f2bf(xv.z); xo[3] = f2bf(xv.w);
        *(bhalf4*)(xb + (size_t)t * H_DIM + 4 * (lane + 64 * j)) = xo;
#pragma unroll
        for (int e = 0; e < E_NUM; ++e) {
            float4 g = ((const float4*)(gw + (size_t)e * H_DIM))[lane + 64 * j];
            acc[e] += xv.x * g.x + xv.y * g.y + xv.z * g.z + xv.w * g.w;
        }
    }
#pragma unroll
    for (int off = 32; off > 0; off >>= 1)
#pragma unroll
        for (int e = 0; e < E_NUM; ++e) acc[e] += __shfl_xor(acc[e], off, 64);

    if (lane == 0) {
        int a = 0; float la = acc[0];
        for (int e = 1; e < E_NUM; ++e) if (acc[e] > la) { la = acc[e]; a = e; }
        int b = (a == 0) ? 1 : 0; float lb = acc[b];
        for (int e = 0; e < E_NUM; ++e)
            if (e != a && acc[e] > lb) { lb = acc[e]; b = e; }
        float wa = 1.f / (1.f + expf(lb - la));
        wts[t * 2 + 0] = wa;
        wts[t * 2 + 1] = 1.f - wa;
        int p0 = atomicAdd(&counts[a], 1); entries[a * T_TOK + p0] = t * 2;
        int p1 = atomicAdd(&counts[b], 1); entries[b * T_TOK + p1] = t * 2 + 1;
    }
}

// ---------------- gemm1: act[v] = silu(x.Wg^T) * (x.Wu^T) ----------------
// M=128 gathered rows x (64 G-cols + 64 U-cols); BK=32; dbuf LDS, 1 barrier/K-step.
__global__ __launch_bounds__(256)
void moe_mfma1(const u16* __restrict__ xb, const float* __restrict__ w1,
               const int* __restrict__ counts, const int* __restrict__ entries,
               u16* __restrict__ act) {
    const int e = blockIdx.z, tn = blockIdx.y, tm = blockIdx.x;  // tm fastest
    const int ne = counts[e];
    if (tm * 128 >= ne) return;

    __shared__ __align__(16) u16 As[2][128 * 32];
    __shared__ __align__(16) u16 Bg[2][64 * 32];
    __shared__ __align__(16) u16 Bu[2][64 * 32];
    __shared__ int rowv[128];

    const int tid = threadIdx.x;
    if (tid < 128) {
        int r = tm * 128 + tid;
        rowv[tid] = (r < ne) ? entries[(size_t)e * T_TOK + r] : -1;
    }
    __syncthreads();

    const u16* asrc[2]; int adsti[2];
#pragma unroll
    for (int q = 0; q < 2; ++q) {
        int i = q * 256 + tid;
        int row = i >> 2, p = i & 3;
        int lc = p ^ swz(row);
        int v = rowv[row]; int tok = (v < 0) ? 0 : (v >> 1);
        asrc[q] = xb + (size_t)tok * H_DIM + lc * 8;
        adsti[q] = i * 8;
    }
    const int brow = tid >> 2, bp = tid & 3;
    const int blc  = bp ^ swz(brow);
    const float* gptr = w1 + ((size_t)e * I2 + tn * 64 + brow) * H_DIM + blc * 8;
    const float* uptr = gptr + (size_t)I_DIM * H_DIM;

    const int lane = tid & 63, wid = tid >> 6;
    const int wm = wid & 1, wn = wid >> 1;

    floatx4 accG[4][2], accU[4][2];
    const floatx4 z4 = {0.f, 0.f, 0.f, 0.f};
#pragma unroll
    for (int mi = 0; mi < 4; ++mi)
#pragma unroll
        for (int ni = 0; ni < 2; ++ni) { accG[mi][ni] = z4; accU[mi][ni] = z4; }

    int aoff[4], boff[2];
#pragma unroll
    for (int mi = 0; mi < 4; ++mi) {
        int m = wm * 64 + mi * 16 + (lane & 15);
        aoff[mi] = m * 32 + (((lane >> 4) ^ swz(m)) * 8);
    }
#pragma unroll
    for (int ni = 0; ni < 2; ++ni) {
        int n = wn * 32 + ni * 16 + (lane & 15);
        boff[ni] = n * 32 + (((lane >> 4) ^ swz(n)) * 8);
    }

    // prologue: B(0) -> regs, A(0) -> buf0
    float4 g0 = *(const float4*)gptr, g1 = *(const float4*)(gptr + 4);
    float4 u0 = *(const float4*)uptr, u1 = *(const float4*)(uptr + 4);
    gload16(asrc[0], &As[0][adsti[0]]);
    gload16(asrc[1], &As[0][adsti[1]]);

    for (int it = 0; it < H_DIM / 32; ++it) {
        const int cb = it & 1;
        *(bhalf8*)&Bg[cb][tid * 8] = pack8(g0, g1);    // waits on B(it) regs
        *(bhalf8*)&Bu[cb][tid * 8] = pack8(u0, u1);
        __syncthreads();                               // drains A(it) gload + B writes + prev reads
        if (it + 1 < H_DIM / 32) {
            const int kn = (it + 1) * 32;
            g0 = *(const float4*)(gptr + kn); g1 = *(const float4*)(gptr + kn + 4);
            u0 = *(const float4*)(uptr + kn); u1 = *(const float4*)(uptr + kn + 4);
            gload16(asrc[0] + kn, &As[cb ^ 1][adsti[0]]);
            gload16(asrc[1] + kn, &As[cb ^ 1][adsti[1]]);
        }
        short8 a[4], bg[2], bu[2];
#pragma unroll
        for (int mi = 0; mi < 4; ++mi) a[mi] = *(const short8*)&As[cb][aoff[mi]];
#pragma unroll
        for (int ni = 0; ni < 2; ++ni) {
            bg[ni] = *(const short8*)&Bg[cb][boff[ni]];
            bu[ni] = *(const short8*)&Bu[cb][boff[ni]];
        }
#pragma unroll
        for (int mi = 0; mi < 4; ++mi)
#pragma unroll
            for (int ni = 0; ni < 2; ++ni) {
                accG[mi][ni] = mfma16(a[mi], bg[ni], accG[mi][ni]);
                accU[mi][ni] = mfma16(a[mi], bu[ni], accU[mi][ni]);
            }
    }

    const int obase = tn * 64 + wn * 32;
#pragma unroll
    for (int mi = 0; mi < 4; ++mi)
#pragma unroll
        for (int ni = 0; ni < 2; ++ni)
#pragma unroll
            for (int r = 0; r < 4; ++r) {
                int row = wm * 64 + mi * 16 + (lane >> 4) * 4 + r;
                int v = rowv[row];
                if (v < 0) continue;
                float g = accG[mi][ni][r], u = accU[mi][ni][r];
                float s = g / (1.f + expf(-g)) * u;
                act[(size_t)v * I_DIM + obase + ni * 16 + (lane & 15)] = f2bf(s);
            }
}

// ---------------- gemm2: out[t] += wts[v] * act[v].W2^T ----------------
// M=128 gathered act rows x N=128 h-cols; BK=32; dbuf LDS, 1 barrier/K-step.
__global__ __launch_bounds__(256)
void moe_mfma2(const u16* __restrict__ act, const float* __restrict__ w2,
               const int* __restrict__ counts, const int* __restrict__ entries,
               const float* __restrict__ wts, float* __restrict__ out) {
    const int e = blockIdx.z, tn = blockIdx.y, tm = blockIdx.x;  // tm fastest
    const int ne = counts[e];
    if (tm * 128 >= ne) return;

    __shared__ __align__(16) u16 As[2][128 * 32];
    __shared__ __align__(16) u16 Bs[2][128 * 32];
    __shared__ int   rowv[128];
    __shared__ int   rowt[128];
    __shared__ float roww[128];

    const int tid = threadIdx.x;
    if (tid < 128) {
        int r = tm * 128 + tid;
        int v = (r < ne) ? entries[(size_t)e * T_TOK + r] : -1;
        rowv[tid] = v;
        rowt[tid] = (v < 0) ? 0 : (v >> 1);
        roww[tid] = (v < 0) ? 0.f : wts[v];
    }
    __syncthreads();

    const u16* asrc[2]; int adsti[2];
    const float* bptr[2]; int bdsti[2];
#pragma unroll
    for (int q = 0; q < 2; ++q) {
        int i = q * 256 + tid;
        int row = i >> 2, p = i & 3;
        int lc = p ^ swz(row);
        int v = rowv[row]; if (v < 0) v = 0;
        asrc[q] = act + (size_t)v * I_DIM + lc * 8;
        adsti[q] = i * 8;
        bptr[q] = w2 + ((size_t)e * H_DIM + tn * 128 + row) * I_DIM + lc * 8;
        bdsti[q] = i * 8;
    }

    const int lane = tid & 63, wid = tid >> 6;
    const int wm = wid & 1, wn = wid >> 1;

    floatx4 acc[4][4];
    const floatx4 z4 = {0.f, 0.f, 0.f, 0.f};
#pragma unroll
    for (int mi = 0; mi < 4; ++mi)
#pragma unroll
        for (int ni = 0; ni < 4; ++ni) acc[mi][ni] = z4;

    int aoff[4], boff[4];
#pragma unroll
    for (int mi = 0; mi < 4; ++mi) {
        int m = wm * 64 + mi * 16 + (lane & 15);
        aoff[mi] = m * 32 + (((lane >> 4) ^ swz(m)) * 8);
    }
#pragma unroll
    for (int ni = 0; ni < 4; ++ni) {
        int n = wn * 64 + ni * 16 + (lane & 15);
        boff[ni] = n * 32 + (((lane >> 4) ^ swz(n)) * 8);
    }

    float4 b00 = *(const float4*)bptr[0], b01 = *(const float4*)(bptr[0] + 4);
    float4 b10 = *(const float4*)bptr[1], b11 = *(const float4*)(bptr[1] + 4);
    gload16(asrc[0], &As[0][adsti[0]]);
    gload16(asrc[1], &As[0][adsti[1]]);

    for (int it = 0; it < I_DIM / 32; ++it) {
        const int cb = it & 1;
        *(bhalf8*)&Bs[cb][bdsti[0]] = pack8(b00, b01);
        *(bhalf8*)&Bs[cb][bdsti[1]] = pack8(b10, b11);
        __syncthreads();
        if (it + 1 < I_DIM / 32) {
            const int kn = (it + 1) * 32;
            b00 = *(const float4*)(bptr[0] + kn); b01 = *(const float4*)(bptr[0] + kn + 4);
            b10 = *(const float4*)(bptr[1] + kn); b11 = *(const float4*)(bptr[1] + kn + 4);
            gload16(asrc[0] + kn, &As[cb ^ 1][adsti[0]]);
            gload16(asrc[1] + kn, &As[cb ^ 1][adsti[1]]);
        }
        short8 a[4], b[4];
#pragma unroll
        for (int mi = 0; mi < 4; ++mi) a[mi] = *(const short8*)&As[cb][aoff[mi]];
#pragma unroll
        for (int ni = 0; ni < 4; ++ni) b[ni] = *(const short8*)&Bs[cb][boff[ni]];
#pragma unroll
        for (int mi = 0; mi < 4; ++mi)
#pragma unroll
            for (int ni = 0; ni < 4; ++ni)
                acc[mi][ni] = mfma16(a[mi], b[ni], acc[mi][ni]);
    }

    const int hbase = tn * 128 + wn * 64;
#pragma unroll
    for (int mi = 0; mi < 4; ++mi)
#pragma unroll
        for (int ni = 0; ni < 4; ++ni)
#pragma unroll
            for (int r = 0; r < 4; ++r) {
                int row = wm * 64 + mi * 16 + (lane >> 4) * 4 + r;
                if (rowv[row] < 0) continue;
                atomicAdd(out + (size_t)rowt[row] * H_DIM + hbase + ni * 16 + (lane & 15),
                          roww[row] * acc[mi][ni][r]);
            }
}

extern "C" void kernel_launch(void* const* d_in, const int* in_sizes, int n_in,
                              void* d_out, int out_size, void* d_ws, size_t ws_size,
                              hipStream_t stream) {
    const float* x  = (const float*)d_in[0];   // [T, H]
    const float* gw = (const float*)d_in[1];   // [E, H]
    const float* w1 = (const float*)d_in[2];   // [E, 2I, H]
    const float* w2 = (const float*)d_in[3];   // [E, H, I]
    float* out = (float*)d_out;                // [T, H]

    char* ws = (char*)d_ws;
    int*   counts  = (int*)ws;                       // 256 B
    int*   entries = (int*)(ws + 256);               // 64 KB
    float* wts     = (float*)(ws + 256 + 65536);     // 16 KB
    u16* xb  = (u16*)(ws + 131072);                  // 8 MB
    u16* act = xb + (size_t)T_TOK * H_DIM;           // 11.5 MB

    (void)hipMemsetAsync(counts, 0, 256, stream);
    (void)hipMemsetAsync(out, 0, (size_t)T_TOK * H_DIM * sizeof(float), stream);

    moe_gating<<<T_TOK / 4, 256, 0, stream>>>(x, gw, wts, counts, entries, xb);
    moe_mfma1<<<dim3(16, I_DIM / 64, E_NUM), 256, 0, stream>>>(xb, w1, counts, entries, act);
    moe_mfma2<<<dim3(16, H_DIM / 128, E_NUM), 256, 0, stream>>>(act, w2, counts, entries, wts, out);
}

// Round 5
// 744.582 us; speedup vs baseline: 1.1453x; 1.1453x over previous
//
#include <hip/hip_runtime.h>
#include <hip/hip_bf16.h>
#include <math.h>

// EnhancedSparseMoE round 5: round-2 proven single-buffer all-gload16 loop,
// bf16 pre-converted weights, M=256 tiles, atomic-free combine via eo scratch.
// T=2048, H=2048, I=1408, E=8, top-2.
#define T_TOK 2048
#define H_DIM 2048
#define I_DIM 1408
#define E_NUM 8
#define I2    2816   // 2*I

typedef __attribute__((ext_vector_type(8))) short short8;
typedef __attribute__((ext_vector_type(4))) float floatx4;
typedef __attribute__((ext_vector_type(8))) unsigned short bhalf8;
typedef __attribute__((ext_vector_type(4))) unsigned short bhalf4;
typedef unsigned short u16;

__device__ __forceinline__ u16 f2bf(float x) {   // RNE, == __float2bfloat16
    unsigned u = __builtin_bit_cast(unsigned, x);
    return (u16)((u + 0x7FFFu + ((u >> 16) & 1u)) >> 16);
}
__device__ __forceinline__ floatx4 mfma16(short8 a, short8 b, floatx4 c) {
    return __builtin_amdgcn_mfma_f32_16x16x32_bf16(a, b, c, 0, 0, 0);
}
__device__ __forceinline__ void gload16(const u16* g, u16* l) {
    __builtin_amdgcn_global_load_lds(
        (const __attribute__((address_space(1))) unsigned int*)g,
        (__attribute__((address_space(3))) unsigned int*)l, 16, 0, 0);
}
// 16B-chunk swizzle: row r, logical chunk c stored at phys chunk c ^ swz(r)
__device__ __forceinline__ int swz(int r) { return (r & 3) ^ ((r >> 2) & 3); }

// ---------------- gating (fp32 exact) + x -> bf16 ----------------
__global__ void moe_gating(const float* __restrict__ x, const float* __restrict__ gw,
                           float* __restrict__ wts, int* __restrict__ counts,
                           int* __restrict__ entries, u16* __restrict__ xb) {
    const int lane = threadIdx.x & 63;
    const int wv   = threadIdx.x >> 6;
    const int t    = blockIdx.x * 4 + wv;
    float acc[E_NUM];
#pragma unroll
    for (int e = 0; e < E_NUM; ++e) acc[e] = 0.f;
    const float4* xr = (const float4*)(x + (size_t)t * H_DIM);
#pragma unroll
    for (int j = 0; j < 8; ++j) {
        float4 xv = xr[lane + 64 * j];
        bhalf4 xo;
        xo[0] = f2bf(xv.x); xo[1] = f2bf(xv.y); xo[2] = f2bf(xv.z); xo[3] = f2bf(xv.w);
        *(bhalf4*)(xb + (size_t)t * H_DIM + 4 * (lane + 64 * j)) = xo;
#pragma unroll
        for (int e = 0; e < E_NUM; ++e) {
            float4 g = ((const float4*)(gw + (size_t)e * H_DIM))[lane + 64 * j];
            acc[e] += xv.x * g.x + xv.y * g.y + xv.z * g.z + xv.w * g.w;
        }
    }
#pragma unroll
    for (int off = 32; off > 0; off >>= 1)
#pragma unroll
        for (int e = 0; e < E_NUM; ++e) acc[e] += __shfl_xor(acc[e], off, 64);

    if (lane == 0) {
        int a = 0; float la = acc[0];
        for (int e = 1; e < E_NUM; ++e) if (acc[e] > la) { la = acc[e]; a = e; }
        int b = (a == 0) ? 1 : 0; float lb = acc[b];
        for (int e = 0; e < E_NUM; ++e)
            if (e != a && acc[e] > lb) { lb = acc[e]; b = e; }
        float wa = 1.f / (1.f + expf(lb - la));
        wts[t * 2 + 0] = wa;
        wts[t * 2 + 1] = 1.f - wa;
        int p0 = atomicAdd(&counts[a], 1); entries[a * T_TOK + p0] = t * 2;
        int p1 = atomicAdd(&counts[b], 1); entries[b * T_TOK + p1] = t * 2 + 1;
    }
}

// ---------------- fp32 -> bf16 bulk convert ----------------
__global__ __launch_bounds__(256)
void cvt_bf16(const float* __restrict__ src, u16* __restrict__ dst, int n8) {
    int i = blockIdx.x * 256 + threadIdx.x;
    if (i >= n8) return;
    const float4* s4 = (const float4*)src;
    float4 a = s4[2 * i], b = s4[2 * i + 1];
    bhalf8 o;
    o[0] = f2bf(a.x); o[1] = f2bf(a.y); o[2] = f2bf(a.z); o[3] = f2bf(a.w);
    o[4] = f2bf(b.x); o[5] = f2bf(b.y); o[6] = f2bf(b.z); o[7] = f2bf(b.w);
    *(bhalf8*)(dst + (size_t)i * 8) = o;
}

// ---------------- gemm1: act[v] = silu(x.Wg^T) * (x.Wu^T) ----------------
// M=256 gathered rows x (64 G-cols + 64 U-cols); BK=32; single-buf, 2 barriers.
__global__ __launch_bounds__(256, 2)
void moe_mfma1(const u16* __restrict__ xb, const u16* __restrict__ w1b,
               const int* __restrict__ counts, const int* __restrict__ entries,
               u16* __restrict__ act) {
    const int e = blockIdx.z, tn = blockIdx.y, tm = blockIdx.x;  // tm fastest
    const int ne = counts[e];
    if (tm * 256 >= ne) return;

    __shared__ __align__(16) u16 As[256 * 32];   // 16 KB
    __shared__ __align__(16) u16 Bg[64 * 32];    // 4 KB
    __shared__ __align__(16) u16 Bu[64 * 32];    // 4 KB
    __shared__ int rowv[256];

    const int tid = threadIdx.x;
    {
        int r = tm * 256 + tid;
        rowv[tid] = (r < ne) ? entries[(size_t)e * T_TOK + r] : -1;
    }
    __syncthreads();

    // A staging: 4 chunks/thread (256 rows x 32 k)
    const u16* asrc[4]; int adsti[4];
#pragma unroll
    for (int q = 0; q < 4; ++q) {
        int i = q * 256 + tid;
        int row = i >> 2, p = i & 3;
        int lc = p ^ swz(row);
        int v = rowv[row]; int tok = (v < 0) ? 0 : (v >> 1);
        asrc[q] = xb + (size_t)tok * H_DIM + lc * 8;
        adsti[q] = i * 8;
    }
    // B staging: 1 chunk/thread for each of G and U (64 rows x 32 k)
    const int brow = tid >> 2, bp = tid & 3;
    const int blc  = bp ^ swz(brow);
    const u16* gsrc = w1b + ((size_t)e * I2 + tn * 64 + brow) * H_DIM + blc * 8;
    const u16* usrc = gsrc + (size_t)I_DIM * H_DIM;

    const int lane = tid & 63, wid = tid >> 6;
    const int wm = wid & 1, wn = wid >> 1;

    floatx4 accG[8][2], accU[8][2];
    const floatx4 z4 = {0.f, 0.f, 0.f, 0.f};
#pragma unroll
    for (int mi = 0; mi < 8; ++mi)
#pragma unroll
        for (int ni = 0; ni < 2; ++ni) { accG[mi][ni] = z4; accU[mi][ni] = z4; }

    int aoff[8], boff[2];
#pragma unroll
    for (int mi = 0; mi < 8; ++mi) {
        int m = wm * 128 + mi * 16 + (lane & 15);
        aoff[mi] = m * 32 + (((lane >> 4) ^ swz(m)) * 8);
    }
#pragma unroll
    for (int ni = 0; ni < 2; ++ni) {
        int n = wn * 32 + ni * 16 + (lane & 15);
        boff[ni] = n * 32 + (((lane >> 4) ^ swz(n)) * 8);
    }

    for (int k0 = 0; k0 < H_DIM; k0 += 32) {
#pragma unroll
        for (int q = 0; q < 4; ++q) gload16(asrc[q] + k0, &As[adsti[q]]);
        gload16(gsrc + k0, &Bg[tid * 8]);
        gload16(usrc + k0, &Bu[tid * 8]);
        __syncthreads();
        short8 bg[2], bu[2];
#pragma unroll
        for (int ni = 0; ni < 2; ++ni) {
            bg[ni] = *(const short8*)&Bg[boff[ni]];
            bu[ni] = *(const short8*)&Bu[boff[ni]];
        }
#pragma unroll
        for (int mi = 0; mi < 8; ++mi) {
            short8 a = *(const short8*)&As[aoff[mi]];
#pragma unroll
            for (int ni = 0; ni < 2; ++ni) {
                accG[mi][ni] = mfma16(a, bg[ni], accG[mi][ni]);
                accU[mi][ni] = mfma16(a, bu[ni], accU[mi][ni]);
            }
        }
        __syncthreads();
    }

    const int obase = tn * 64 + wn * 32;
#pragma unroll
    for (int mi = 0; mi < 8; ++mi)
#pragma unroll
        for (int ni = 0; ni < 2; ++ni)
#pragma unroll
            for (int r = 0; r < 4; ++r) {
                int row = wm * 128 + mi * 16 + (lane >> 4) * 4 + r;
                int v = rowv[row];
                if (v < 0) continue;
                float g = accG[mi][ni][r], u = accU[mi][ni][r];
                float s = g / (1.f + expf(-g)) * u;
                act[(size_t)v * I_DIM + obase + ni * 16 + (lane & 15)] = f2bf(s);
            }
}

// ---------------- gemm2: eo[v] = act[v].W2^T (fp32, no atomics) ----------------
// M=256 gathered act rows x N=128 h-cols; BK=32; single-buf, 2 barriers.
__global__ __launch_bounds__(256, 2)
void moe_mfma2(const u16* __restrict__ act, const u16* __restrict__ w2b,
               const int* __restrict__ counts, const int* __restrict__ entries,
               float* __restrict__ eo) {
    const int e = blockIdx.z, tn = blockIdx.y, tm = blockIdx.x;  // tm fastest
    const int ne = counts[e];
    if (tm * 256 >= ne) return;

    __shared__ __align__(16) u16 As[256 * 32];   // 16 KB
    __shared__ __align__(16) u16 Bs[128 * 32];   // 8 KB
    __shared__ int rowv[256];

    const int tid = threadIdx.x;
    {
        int r = tm * 256 + tid;
        rowv[tid] = (r < ne) ? entries[(size_t)e * T_TOK + r] : -1;
    }
    __syncthreads();

    const u16* asrc[4]; int adsti[4];
#pragma unroll
    for (int q = 0; q < 4; ++q) {
        int i = q * 256 + tid;
        int row = i >> 2, p = i & 3;
        int lc = p ^ swz(row);
        int v = rowv[row]; if (v < 0) v = 0;
        asrc[q] = act + (size_t)v * I_DIM + lc * 8;
        adsti[q] = i * 8;
    }
    const u16* bsrc[2]; int bdsti[2];
#pragma unroll
    for (int q = 0; q < 2; ++q) {
        int i = q * 256 + tid;
        int row = i >> 2, p = i & 3;
        int lc = p ^ swz(row);
        bsrc[q] = w2b + ((size_t)e * H_DIM + tn * 128 + row) * I_DIM + lc * 8;
        bdsti[q] = i * 8;
    }

    const int lane = tid & 63, wid = tid >> 6;
    const int wm = wid & 1, wn = wid >> 1;

    floatx4 acc[8][4];
    const floatx4 z4 = {0.f, 0.f, 0.f, 0.f};
#pragma unroll
    for (int mi = 0; mi < 8; ++mi)
#pragma unroll
        for (int ni = 0; ni < 4; ++ni) acc[mi][ni] = z4;

    int aoff[8], boff[4];
#pragma unroll
    for (int mi = 0; mi < 8; ++mi) {
        int m = wm * 128 + mi * 16 + (lane & 15);
        aoff[mi] = m * 32 + (((lane >> 4) ^ swz(m)) * 8);
    }
#pragma unroll
    for (int ni = 0; ni < 4; ++ni) {
        int n = wn * 64 + ni * 16 + (lane & 15);
        boff[ni] = n * 32 + (((lane >> 4) ^ swz(n)) * 8);
    }

    for (int k0 = 0; k0 < I_DIM; k0 += 32) {
#pragma unroll
        for (int q = 0; q < 4; ++q) gload16(asrc[q] + k0, &As[adsti[q]]);
#pragma unroll
        for (int q = 0; q < 2; ++q) gload16(bsrc[q] + k0, &Bs[bdsti[q]]);
        __syncthreads();
        short8 b[4];
#pragma unroll
        for (int ni = 0; ni < 4; ++ni) b[ni] = *(const short8*)&Bs[boff[ni]];
#pragma unroll
        for (int mi = 0; mi < 8; ++mi) {
            short8 a = *(const short8*)&As[aoff[mi]];
#pragma unroll
            for (int ni = 0; ni < 4; ++ni)
                acc[mi][ni] = mfma16(a, b[ni], acc[mi][ni]);
        }
        __syncthreads();
    }

    const int hbase = tn * 128 + wn * 64;
#pragma unroll
    for (int mi = 0; mi < 8; ++mi)
#pragma unroll
        for (int r = 0; r < 4; ++r) {
            int row = wm * 128 + mi * 16 + (lane >> 4) * 4 + r;
            int v = rowv[row];
            if (v < 0) continue;
            float* op = eo + (size_t)v * H_DIM + hbase + (lane & 15);
#pragma unroll
            for (int ni = 0; ni < 4; ++ni) op[ni * 16] = acc[mi][ni][r];
        }
}

// ---------------- combine: out[t] = w0*eo[2t] + w1*eo[2t+1] ----------------
__global__ __launch_bounds__(256)
void moe_combine(const float* __restrict__ eo, const float* __restrict__ wts,
                 float* __restrict__ out) {
    int idx = blockIdx.x * 256 + threadIdx.x;       // one float4 per thread
    int t = idx >> 9, c = idx & 511;                // H/4 = 512
    float w0 = wts[2 * t], w1 = wts[2 * t + 1];
    const float4* e0 = (const float4*)(eo + (size_t)(2 * t) * H_DIM) + c;
    const float4* e1 = (const float4*)(eo + (size_t)(2 * t + 1) * H_DIM) + c;
    float4 a = *e0, b = *e1, o;
    o.x = w0 * a.x + w1 * b.x;
    o.y = w0 * a.y + w1 * b.y;
    o.z = w0 * a.z + w1 * b.z;
    o.w = w0 * a.w + w1 * b.w;
    ((float4*)out)[idx] = o;
}

extern "C" void kernel_launch(void* const* d_in, const int* in_sizes, int n_in,
                              void* d_out, int out_size, void* d_ws, size_t ws_size,
                              hipStream_t stream) {
    const float* x  = (const float*)d_in[0];   // [T, H]
    const float* gw = (const float*)d_in[1];   // [E, H]
    const float* w1 = (const float*)d_in[2];   // [E, 2I, H]
    const float* w2 = (const float*)d_in[3];   // [E, H, I]
    float* out = (float*)d_out;                // [T, H]

    char* ws = (char*)d_ws;
    int*   counts  = (int*)ws;                       // 256 B
    int*   entries = (int*)(ws + 256);               // 64 KB
    float* wts     = (float*)(ws + 256 + 65536);     // 16 KB
    u16* xb  = (u16*)(ws + 131072);                  // 8 MB
    u16* act = xb  + (size_t)T_TOK * H_DIM;          // 11.5 MB
    u16* w1b = act + (size_t)2 * T_TOK * I_DIM;      // 92 MB (dead after mfma1)
    u16* w2b = w1b + (size_t)E_NUM * I2 * H_DIM;     // 46 MB
    float* eo = (float*)w1b;                         // 33.5 MB, aliases w1b

    (void)hipMemsetAsync(counts, 0, 256, stream);

    moe_gating<<<T_TOK / 4, 256, 0, stream>>>(x, gw, wts, counts, entries, xb);
    cvt_bf16<<<(E_NUM * I2 * H_DIM / 8 + 255) / 256, 256, 0, stream>>>(w1, w1b, E_NUM * I2 * H_DIM / 8);
    cvt_bf16<<<(E_NUM * H_DIM * I_DIM / 8 + 255) / 256, 256, 0, stream>>>(w2, w2b, E_NUM * H_DIM * I_DIM / 8);
    moe_mfma1<<<dim3(8, I_DIM / 64, E_NUM), 256, 0, stream>>>(xb, w1b, counts, entries, act);
    moe_mfma2<<<dim3(8, H_DIM / 128, E_NUM), 256, 0, stream>>>(act, w2b, counts, entries, eo);
    moe_combine<<<T_TOK * H_DIM / 4 / 256, 256, 0, stream>>>(eo, wts, out);
}